// Round 29
// baseline (19.281 us; speedup 1.0000x reference)
//
#include <hip/hip_runtime.h>
#include <hip/hip_bf16.h>

// MoE: out[b] = inp[b] @ weight[gate[b]].T
// inp: [4096,512] f32, gate: [4096] int, weight: [32,512,512] f32, out: [4096,512] f32
// Round 29: r28 (best, 17.01us) + DEPTH-3 register banks: loads(t+4) issue after
// WRITE(t+1) -> cover = 3 full iterations (~1200cy > 900cy cold-HBM latency).
// Bank = T%3 (static via full unroll); LDS double buffer stays parity t&1
// (banks are registers, independent). Freed-bank invariant: (t+4)%3 == (t+1)%3,
// the bank WRITE(t+1) just consumed -> no load ever ahead of a drain.
// All else r28-verbatim: 512thr/8 waves, 64x64x64, one drain+barrier/iter
// (race-free proof unchanged), mask prep, W tile-0 pre-prep issue, 16B
// ds_writes, XOR swizzle, TMAX=3/grid 768, clamped pad rows, XCD swizzle.

#define NE     32
#define NBATCH 4096
#define KF     512
#define NF     512
#define BM     64
#define BN     64
#define BK     64
#define NKT    (KF / BK)     // 8
#define TMAX   3
#define NCHUNK 64
#define NWG    (8 * NE * TMAX)  // 768, %8==0 -> bijective XCD swizzle
#define BUFB   ((BM + BN) * BK * 2)  // 16KB per buffer

typedef __attribute__((ext_vector_type(8))) short bf16x8;
typedef __attribute__((ext_vector_type(4))) float f32x4;

__device__ __forceinline__ unsigned cvt2(float lo, float hi) {
    __hip_bfloat162 h = __float22bfloat162_rn(make_float2(lo, hi));
    return *reinterpret_cast<unsigned*>(&h);   // v_cvt_pk_bf16_f32
}

// XOR swizzle within [row][64 bf16] (128B row stride); same bijection write+read.
__device__ __forceinline__ int swz(int row, int col_b) {
    return row * 128 + (col_b ^ ((row & 7) << 4));
}

__global__ __launch_bounds__(512)
void moe_fused(const float* __restrict__ inp,
               const int* __restrict__ gate,
               const float* __restrict__ weight,
               float* __restrict__ out) {
    // bijective XCD-chunk swizzle (768 blocks, 8 XCDs, 96/chunk): XCD k owns
    // experts [4k,4k+4) -> W panels + token rows pinned in that L2.
    const int bid = blockIdx.x;
    const int swb = (bid & 7) * (NWG / 8) + (bid >> 3);
    const int nb    = swb & 7;
    const int y     = swb >> 3;          // 0..95
    const int e     = y / 3;
    const int local = y - e * 3;

    __shared__ __align__(16) unsigned char lds[2 * BUFB];  // 32KB double buffer
    __shared__ int srow[BM];
    __shared__ int chunkinfo[NCHUNK];

    const int tid  = threadIdx.x;
    const int lane = tid & 63;
    const int wid  = tid >> 6;           // 0..7

    // staging map (16B granule): thread covers row tid>>3 (0..63) at float col
    // (tid&7)*8 -- one 16B A-slot and one 16B W-slot after cvt.
    const int srow_r = tid >> 3;         // 0..63
    const int c8     = (tid & 7) * 8;    // float offset of first float4
    const int nblk   = nb * BN;
    const float* wbase = weight + (size_t)e * (NF * KF) + (size_t)nblk * KF;

    float4 ra[3][2], rw[3][2];           // [bank][half]; bank = tile % 3

    // ---- W tile-0 issued BEFORE prep: only needs e; latency hides under prep ----
    rw[0][0] = *(const float4*)(wbase + (size_t)srow_r * KF + c8);
    rw[0][1] = *(const float4*)(wbase + (size_t)srow_r * KF + c8 + 4);
    asm volatile("" ::: "memory");       // pin: issue now, don't sink into prep

    // ---- self-prep (512-thread): int4 gate loads + 8-bit mask + segment scan ----
    // thread owns gates [tid*8, tid*8+8), all inside chunk tid>>3
    int4 gv[2];
#pragma unroll
    for (int j = 0; j < 2; ++j)
        gv[j] = ((const int4*)gate)[tid * 2 + j];

    unsigned mask = 0;
#pragma unroll
    for (int j = 0; j < 2; ++j) {
        if (gv[j].x == e) mask |= 1u << (j * 4 + 0);
        if (gv[j].y == e) mask |= 1u << (j * 4 + 1);
        if (gv[j].z == e) mask |= 1u << (j * 4 + 2);
        if (gv[j].w == e) mask |= 1u << (j * 4 + 3);
    }
    const int cnt = __popc(mask);

    // inclusive scan over the 8 threads of this chunk (lanes grouped by 8)
    int xs = cnt;
    {
        int u = __shfl_up(xs, 1, 8); if ((lane & 7) >= 1) xs += u;
        u     = __shfl_up(xs, 2, 8); if ((lane & 7) >= 2) xs += u;
        u     = __shfl_up(xs, 4, 8); if ((lane & 7) >= 4) xs += u;
    }
    const int pre = xs - cnt;            // exclusive prefix within chunk
    if ((lane & 7) == 7) chunkinfo[tid >> 3] = xs;   // chunk total
    if (tid < BM) srow[tid] = -1;
    __syncthreads();                     // barrier 1: chunk counts + srow init

    // per-wave redundant scan of all 64 chunk counts (no cross-wave exchange)
    int cc = chunkinfo[lane];
    int x  = cc;
#pragma unroll
    for (int d = 1; d < 64; d <<= 1) {
        int u = __shfl_up(x, d, 64);
        if (lane >= d) x += u;
    }
    const int excl  = x - cc;            // lane l holds exclusive base of chunk l
    const int total = __shfl(x, 63, 64);

    // shfl with ALL lanes active (r18 bug fix); source lane = wid*8+(lane>>3),
    // valid 0..63 within this wave (each wave holds the full redundant scan).
    const int chunkbase = __shfl(excl, tid >> 3, 64);

    const int m0 = local * BM;
    if (m0 >= total) return;             // block-uniform exit (no barrier pending)

    // scatter: rank = own-chunk base + within-chunk prefix + intra-thread order
    if (mask) {
        int rr = chunkbase + pre;
        unsigned mm = mask;
        while (mm) {
            int j = __ffs(mm) - 1;
            mm &= mm - 1;
            if (rr >= m0 && rr < m0 + BM)
                srow[rr - m0] = tid * 8 + j;
            ++rr;
        }
    }
    __syncthreads();                     // barrier 2: srow ready

    const int wm = wid & 3;              // 4 m-quarters (16 rows)
    const int wn = wid >> 2;             // 2 n-halves (32 cols)

    const int arow0 = srow[srow_r];
    // clamp pad rows to row 0: real data, outputs never stored (r14-validated)
    const float* ap = inp + (size_t)(arow0 < 0 ? 0 : arow0) * KF + c8;

#define LOADA(B, T) do { const int k0 = (T) * BK;                                    \
    ra[B][0] = *(const float4*)(ap + k0);                                            \
    ra[B][1] = *(const float4*)(ap + k0 + 4); } while (0)

#define LOADW(B, T) do { const int k0 = (T) * BK;                                    \
    rw[B][0] = *(const float4*)(wbase + (size_t)srow_r * KF + k0 + c8);              \
    rw[B][1] = *(const float4*)(wbase + (size_t)srow_r * KF + k0 + c8 + 4); } while (0)

#define WRITE_TILE(B, L) do { const int cb = (tid & 7) * 16;                         \
    unsigned char* Lb = lds + (L) * BUFB;                                            \
    { uint4 p = make_uint4(cvt2(ra[B][0].x, ra[B][0].y), cvt2(ra[B][0].z, ra[B][0].w), \
                           cvt2(ra[B][1].x, ra[B][1].y), cvt2(ra[B][1].z, ra[B][1].w)); \
      *(uint4*)(Lb + swz(srow_r, cb)) = p; }                                         \
    { uint4 p = make_uint4(cvt2(rw[B][0].x, rw[B][0].y), cvt2(rw[B][0].z, rw[B][0].w), \
                           cvt2(rw[B][1].x, rw[B][1].y), cvt2(rw[B][1].z, rw[B][1].w)); \
      *(uint4*)(Lb + 8192 + swz(srow_r, cb)) = p; } } while (0)

    f32x4 acc[2];
    acc[0] = (f32x4)(0.f);
    acc[1] = (f32x4)(0.f);

#define COMPUTE(L) do { const unsigned char* Lb = lds + (L) * BUFB;                  \
    _Pragma("unroll") for (int kk = 0; kk < 2; ++kk) {                               \
        const int kb = kk * 64 + 16 * (lane >> 4);                                   \
        int rA = wm * 16 + (lane & 15);                                              \
        bf16x8 af = *(const bf16x8*)(Lb + swz(rA, kb));                              \
        bf16x8 bfr[2];                                                               \
        _Pragma("unroll") for (int ni = 0; ni < 2; ++ni) {                           \
            int r = wn * 32 + ni * 16 + (lane & 15);                                 \
            bfr[ni] = *(const bf16x8*)(Lb + 8192 + swz(r, kb)); }                    \
        _Pragma("unroll") for (int ni = 0; ni < 2; ++ni)                             \
            acc[ni] = __builtin_amdgcn_mfma_f32_16x16x32_bf16(                       \
                af, bfr[ni], acc[ni], 0, 0, 0); } } while (0)

    // ---- depth-3 pipelined K-loop, loads AFTER the consuming WRITE ----
    // bank = tile % 3; lds buf = tile & 1.
    // prologue: tile-0 staged; tiles 1,2,3 in flight (banks 1,2,0-after-free)
    LOADA(0, 0);                         // bank0 (W tile-0 already in flight)
    asm volatile("" ::: "memory");
    WRITE_TILE(0, 0);                    // consumes bank0 (vmcnt waits tile-0 only)
    LOADA(1, 1); LOADW(1, 1);            // bank1 -> WRITE(1) at iter 0
    LOADA(2, 2); LOADW(2, 2);            // bank2 -> WRITE(2) at iter 1
    LOADA(0, 3); LOADW(0, 3);            // bank0 (freed) -> WRITE(3) at iter 2
    asm volatile("" ::: "memory");       // pin above drain+barrier
    asm volatile("s_waitcnt lgkmcnt(0)" ::: "memory");
    __builtin_amdgcn_s_barrier();        // buf0 ready; tiles 1-3 in flight

#pragma unroll
    for (int t = 0; t < NKT; ++t) {      // full unroll: static bank indices
        COMPUTE(t & 1);                  // reads lds buf[cur]
        if (t + 1 < NKT) {
            WRITE_TILE((t + 1) % 3, (t + 1) & 1);  // bank loaded 3 iters ago
            if (t + 4 < NKT) {
                LOADA((t + 4) % 3, t + 4);  // == (t+1)%3: bank just freed;
                LOADW((t + 4) % 3, t + 4);  // never in front of a drain
                asm volatile("" ::: "memory");
            }
            asm volatile("s_waitcnt lgkmcnt(0)" ::: "memory");  // reads+writes
            __builtin_amdgcn_s_barrier();
        }
    }
#undef LOADA
#undef LOADW
#undef WRITE_TILE
#undef COMPUTE

    // ---- epilogue: D frag col=lane&15 (n), row=(lane>>4)*4+q (m) ----
#pragma unroll
    for (int q = 0; q < 4; ++q) {
        int m = wm * 16 + (lane >> 4) * 4 + q;
        int row = srow[m];
        if (row >= 0) {
#pragma unroll
            for (int ni = 0; ni < 2; ++ni)
                out[(size_t)row * NF + nblk + wn * 32 + ni * 16 + (lane & 15)]
                    = acc[ni][q];
        }
    }
}

extern "C" void kernel_launch(void* const* d_in, const int* in_sizes, int n_in,
                              void* d_out, int out_size, void* d_ws, size_t ws_size,
                              hipStream_t stream) {
    const float* inp    = (const float*)d_in[0];
    const int*   gate   = (const int*)d_in[1];
    const float* weight = (const float*)d_in[2];
    float*       out    = (float*)d_out;

    moe_fused<<<NWG, 512, 0, stream>>>(inp, gate, weight, out);
}

// Round 30
// 16.953 us; speedup vs baseline: 1.1373x; 1.1373x over previous
//
#include <hip/hip_runtime.h>
#include <hip/hip_bf16.h>

// MoE: out[b] = inp[b] @ weight[gate[b]].T
// inp: [4096,512] f32, gate: [4096] int, weight: [32,512,512] f32, out: [4096,512] f32
// FINAL (= round 28, best sound kernel, 17.01us): 512thr/8 waves, 64x64x64
// double-buffered bf16-MFMA grouped GEMM, fused ballot-prep, depth-2 register
// banks with loads issued AFTER the consuming WRITE (full-iteration cover, no
// load ever ahead of a drain), ONE lgkm-drain + barrier per K-iteration
// (race-free: reads of buf X drain at iter t's barrier; next write to X is
// after it), 16B ds_writes, XOR-swizzled LDS (both sides), W tile-0 issued
// before prep, TMAX=3/grid 768, clamped pad rows, bijective XCD-chunk swizzle.
// r29's depth-3 regressed (VGPR=44: banks demoted to scratch) -> depth-2 is
// the saturation point of the issue-distance lever.

#define NE     32
#define NBATCH 4096
#define KF     512
#define NF     512
#define BM     64
#define BN     64
#define BK     64
#define NKT    (KF / BK)     // 8
#define TMAX   3
#define NCHUNK 64
#define NWG    (8 * NE * TMAX)  // 768, %8==0 -> bijective XCD swizzle
#define BUFB   ((BM + BN) * BK * 2)  // 16KB per buffer

typedef __attribute__((ext_vector_type(8))) short bf16x8;
typedef __attribute__((ext_vector_type(4))) float f32x4;

__device__ __forceinline__ unsigned cvt2(float lo, float hi) {
    __hip_bfloat162 h = __float22bfloat162_rn(make_float2(lo, hi));
    return *reinterpret_cast<unsigned*>(&h);   // v_cvt_pk_bf16_f32
}

// XOR swizzle within [row][64 bf16] (128B row stride); same bijection write+read.
__device__ __forceinline__ int swz(int row, int col_b) {
    return row * 128 + (col_b ^ ((row & 7) << 4));
}

__global__ __launch_bounds__(512)
void moe_fused(const float* __restrict__ inp,
               const int* __restrict__ gate,
               const float* __restrict__ weight,
               float* __restrict__ out) {
    // bijective XCD-chunk swizzle (768 blocks, 8 XCDs, 96/chunk): XCD k owns
    // experts [4k,4k+4) -> W panels + token rows pinned in that L2.
    const int bid = blockIdx.x;
    const int swb = (bid & 7) * (NWG / 8) + (bid >> 3);
    const int nb    = swb & 7;
    const int y     = swb >> 3;          // 0..95
    const int e     = y / 3;
    const int local = y - e * 3;

    __shared__ __align__(16) unsigned char lds[2 * BUFB];  // 32KB double buffer
    __shared__ int srow[BM];
    __shared__ int chunkinfo[NCHUNK];

    const int tid  = threadIdx.x;
    const int lane = tid & 63;
    const int wid  = tid >> 6;           // 0..7

    // staging map (16B granule): thread covers row tid>>3 (0..63) at float col
    // (tid&7)*8 -- one 16B A-slot and one 16B W-slot after cvt.
    const int srow_r = tid >> 3;         // 0..63
    const int c8     = (tid & 7) * 8;    // float offset of first float4
    const int nblk   = nb * BN;
    const float* wbase = weight + (size_t)e * (NF * KF) + (size_t)nblk * KF;

    float4 ra[2][2], rw[2][2];           // [bank][half]; bank = tile & 1

    // ---- W tile-0 issued BEFORE prep: only needs e; latency hides under prep ----
    rw[0][0] = *(const float4*)(wbase + (size_t)srow_r * KF + c8);
    rw[0][1] = *(const float4*)(wbase + (size_t)srow_r * KF + c8 + 4);
    asm volatile("" ::: "memory");       // pin: issue now, don't sink into prep

    // ---- self-prep (512-thread): int4 gate loads + 8-bit mask + segment scan ----
    // thread owns gates [tid*8, tid*8+8), all inside chunk tid>>3
    int4 gv[2];
#pragma unroll
    for (int j = 0; j < 2; ++j)
        gv[j] = ((const int4*)gate)[tid * 2 + j];

    unsigned mask = 0;
#pragma unroll
    for (int j = 0; j < 2; ++j) {
        if (gv[j].x == e) mask |= 1u << (j * 4 + 0);
        if (gv[j].y == e) mask |= 1u << (j * 4 + 1);
        if (gv[j].z == e) mask |= 1u << (j * 4 + 2);
        if (gv[j].w == e) mask |= 1u << (j * 4 + 3);
    }
    const int cnt = __popc(mask);

    // inclusive scan over the 8 threads of this chunk (lanes grouped by 8)
    int xs = cnt;
    {
        int u = __shfl_up(xs, 1, 8); if ((lane & 7) >= 1) xs += u;
        u     = __shfl_up(xs, 2, 8); if ((lane & 7) >= 2) xs += u;
        u     = __shfl_up(xs, 4, 8); if ((lane & 7) >= 4) xs += u;
    }
    const int pre = xs - cnt;            // exclusive prefix within chunk
    if ((lane & 7) == 7) chunkinfo[tid >> 3] = xs;   // chunk total
    if (tid < BM) srow[tid] = -1;
    __syncthreads();                     // barrier 1: chunk counts + srow init

    // per-wave redundant scan of all 64 chunk counts (no cross-wave exchange)
    int cc = chunkinfo[lane];
    int x  = cc;
#pragma unroll
    for (int d = 1; d < 64; d <<= 1) {
        int u = __shfl_up(x, d, 64);
        if (lane >= d) x += u;
    }
    const int excl  = x - cc;            // lane l holds exclusive base of chunk l
    const int total = __shfl(x, 63, 64);

    // shfl with ALL lanes active (r18 bug fix); source lane = wid*8+(lane>>3),
    // valid 0..63 within this wave (each wave holds the full redundant scan).
    const int chunkbase = __shfl(excl, tid >> 3, 64);

    const int m0 = local * BM;
    if (m0 >= total) return;             // block-uniform exit (no barrier pending)

    // scatter: rank = own-chunk base + within-chunk prefix + intra-thread order
    if (mask) {
        int rr = chunkbase + pre;
        unsigned mm = mask;
        while (mm) {
            int j = __ffs(mm) - 1;
            mm &= mm - 1;
            if (rr >= m0 && rr < m0 + BM)
                srow[rr - m0] = tid * 8 + j;
            ++rr;
        }
    }
    __syncthreads();                     // barrier 2: srow ready

    const int wm = wid & 3;              // 4 m-quarters (16 rows)
    const int wn = wid >> 2;             // 2 n-halves (32 cols)

    const int arow0 = srow[srow_r];
    // clamp pad rows to row 0: real data, outputs never stored (r14-validated)
    const float* ap = inp + (size_t)(arow0 < 0 ? 0 : arow0) * KF + c8;

#define LOADA(B, T) do { const int k0 = (T) * BK;                                    \
    ra[B][0] = *(const float4*)(ap + k0);                                            \
    ra[B][1] = *(const float4*)(ap + k0 + 4); } while (0)

#define LOADW(B, T) do { const int k0 = (T) * BK;                                    \
    rw[B][0] = *(const float4*)(wbase + (size_t)srow_r * KF + k0 + c8);              \
    rw[B][1] = *(const float4*)(wbase + (size_t)srow_r * KF + k0 + c8 + 4); } while (0)

#define WRITE_TILE(B) do { const int cb = (tid & 7) * 16;                            \
    unsigned char* Lb = lds + (B) * BUFB;                                            \
    { uint4 p = make_uint4(cvt2(ra[B][0].x, ra[B][0].y), cvt2(ra[B][0].z, ra[B][0].w), \
                           cvt2(ra[B][1].x, ra[B][1].y), cvt2(ra[B][1].z, ra[B][1].w)); \
      *(uint4*)(Lb + swz(srow_r, cb)) = p; }                                         \
    { uint4 p = make_uint4(cvt2(rw[B][0].x, rw[B][0].y), cvt2(rw[B][0].z, rw[B][0].w), \
                           cvt2(rw[B][1].x, rw[B][1].y), cvt2(rw[B][1].z, rw[B][1].w)); \
      *(uint4*)(Lb + 8192 + swz(srow_r, cb)) = p; } } while (0)

    f32x4 acc[2];
    acc[0] = (f32x4)(0.f);
    acc[1] = (f32x4)(0.f);

#define COMPUTE(B) do { const unsigned char* Lb = lds + (B) * BUFB;                  \
    _Pragma("unroll") for (int kk = 0; kk < 2; ++kk) {                               \
        const int kb = kk * 64 + 16 * (lane >> 4);                                   \
        int rA = wm * 16 + (lane & 15);                                              \
        bf16x8 af = *(const bf16x8*)(Lb + swz(rA, kb));                              \
        bf16x8 bfr[2];                                                               \
        _Pragma("unroll") for (int ni = 0; ni < 2; ++ni) {                           \
            int r = wn * 32 + ni * 16 + (lane & 15);                                 \
            bfr[ni] = *(const bf16x8*)(Lb + 8192 + swz(r, kb)); }                    \
        _Pragma("unroll") for (int ni = 0; ni < 2; ++ni)                             \
            acc[ni] = __builtin_amdgcn_mfma_f32_16x16x32_bf16(                       \
                af, bfr[ni], acc[ni], 0, 0, 0); } } while (0)

    // ---- depth-2 double-buffered K-loop, loads AFTER the consuming WRITE ----
    // bank = tile & 1; lds buf = tile & 1 (same parity).
    LOADA(0, 0);                         // bank0 (W tile-0 already in flight)
    asm volatile("" ::: "memory");
    WRITE_TILE(0);                       // consumes bank0 (vmcnt waits tile-0 only)
    LOADA(1, 1); LOADW(1, 1);            // bank1 -> used at WRITE(1), iter 0
    LOADA(0, 2); LOADW(0, 2);            // bank0 (freed) -> used at WRITE(2), iter 1
    asm volatile("" ::: "memory");       // pin above drain+barrier
    asm volatile("s_waitcnt lgkmcnt(0)" ::: "memory");
    __builtin_amdgcn_s_barrier();        // buf0 ready; tiles 1,2 in flight

#pragma unroll
    for (int t = 0; t < NKT; ++t) {      // full unroll: static bank indices
        COMPUTE(t & 1);                  // reads lds buf[cur]
        if (t + 1 < NKT) {
            WRITE_TILE((t + 1) & 1);     // consumes bank loaded 2 iters ago
            if (t + 3 < NKT) {
                LOADA((t + 3) & 1, t + 3);  // bank just freed by this WRITE;
                LOADW((t + 3) & 1, t + 3);  // never in front of a drain
                asm volatile("" ::: "memory");
            }
            asm volatile("s_waitcnt lgkmcnt(0)" ::: "memory");  // reads+writes
            __builtin_amdgcn_s_barrier();
        }
    }
#undef LOADA
#undef LOADW
#undef WRITE_TILE
#undef COMPUTE

    // ---- epilogue: D frag col=lane&15 (n), row=(lane>>4)*4+q (m) ----
#pragma unroll
    for (int q = 0; q < 4; ++q) {
        int m = wm * 16 + (lane >> 4) * 4 + q;
        int row = srow[m];
        if (row >= 0) {
#pragma unroll
            for (int ni = 0; ni < 2; ++ni)
                out[(size_t)row * NF + nblk + wn * 32 + ni * 16 + (lane & 15)]
                    = acc[ni][q];
        }
    }
}

extern "C" void kernel_launch(void* const* d_in, const int* in_sizes, int n_in,
                              void* d_out, int out_size, void* d_ws, size_t ws_size,
                              hipStream_t stream) {
    const float* inp    = (const float*)d_in[0];
    const int*   gate   = (const int*)d_in[1];
    const float* weight = (const float*)d_in[2];
    float*       out    = (float*)d_out;

    moe_fused<<<NWG, 512, 0, stream>>>(inp, gate, weight, out);
}